// Round 23
// baseline (178.231 us; speedup 1.0000x reference)
//
#include <hip/hip_runtime.h>

#define B_   8
#define CIN  256
#define H_   128
#define W_   128
#define HO   64
#define WO   64
#define CO_  256
#define NEG  0.2f

typedef __attribute__((ext_vector_type(8))) _Float16 h16x8;
typedef __attribute__((ext_vector_type(4))) float f32x4;
typedef unsigned short u16;

// ws layout (float slots):
//  off    : [8][18][64][64] f32            @ 0         (589824)
//  wdefh  : [9][256][256] fp16             @ 589824    (294912 slots)
//  w1h    : [256][256] fp16                @ 884736    (32768 slots)
//  wboff  : [9][4][32][64] fp16 pre-swz    @ 917504    (36864 slots)
//  y1p    : [8][64][64][256] fp16          @ 954368    (4194304 slots) -- fallback path only
//  xh     : [8][128][128][256] fp16        @ 5148672   (16777216 slots = 64 MB)
//  tap    : [8][64][64][9] x 16B           @ 21925888  (1179648 slots) -- ONLY if ws fits
#define OFF_OFS   0
#define WDEF_OFS  589824
#define W1_OFS    884736
#define WBOFF_OFS 917504
#define Y1_OFS    954368
#define XBF_OFS   5148672
#define TAP_OFS   21925888
#define WS_NEED_TAP ((21925888ull + 1179648ull) * 4ull)   // 92.4 MB

__device__ __forceinline__ float lrelu(float v) { return v >= 0.f ? v : NEG * v; }

__device__ __forceinline__ u16 f2h(float f) {
    _Float16 h = (_Float16)f;           // v_cvt_f16_f32 (RNE)
    return *(u16*)&h;
}

__device__ __forceinline__ void gld16(const void* g, void* l) {
    __builtin_amdgcn_global_load_lds((const __attribute__((address_space(1))) unsigned*)g,
                                     (__attribute__((address_space(3))) unsigned*)l, 16, 0, 0);
}

// ---------------- one-time weight prep (fp16) ----------------
__global__ __launch_bounds__(256) void prep(
    const float* __restrict__ wdef, const float* __restrict__ w1,
    const float* __restrict__ woff,
    u16* __restrict__ wdefh, u16* __restrict__ w1h, u16* __restrict__ wboff)
{
    int i = blockIdx.x * 256 + threadIdx.x;
    if (i < 9 * 256 * 256) {
        int c  = i & 255;
        int co = (i >> 8) & 255;
        int k  = i >> 16;
        wdefh[i] = f2h(wdef[((size_t)co * 256 + c) * 9 + k]);
    }
    if (i < 65536) w1h[i] = f2h(w1[i]);
    if (i < 73728) {
        int j  = i & 7;
        int s  = (i >> 3) & 7;
        int co = (i >> 6) & 31;
        int ch = (i >> 11) & 3;
        int k  = i >> 13;
        int c  = ch * 64 + ((s ^ ((co >> 1) & 7)) << 3) + j;
        wboff[i] = (co < 18) ? f2h(woff[((size_t)co * 256 + c) * 9 + k]) : (u16)0;
    }
}

// ---------------- x: NCHW fp32 -> NHWC fp16 (one-time) ----------------
__global__ __launch_bounds__(256) void nchw2nhwc(
    const float* __restrict__ x, u16* __restrict__ xh)
{
    __shared__ float tile[64][128];   // 32 KB
    int bid = blockIdx.x;
    int g = bid & 3;
    int y = (bid >> 2) & 127;
    int b = bid >> 9;
    int t = threadIdx.x;

    const float* src = x + ((size_t)(b * 256 + g * 64) * 128 + y) * 128;
#pragma unroll
    for (int p = 0; p < 8; ++p) {
        int i = p * 256 + t;
        int cc = i >> 5, x4 = (i & 31) * 4;
        *(float4*)&tile[cc][x4] = *(const float4*)(src + (size_t)cc * 16384 + x4);
    }
    __syncthreads();

    int xpos = t >> 1, h = t & 1;
    u16 buf[32];
#pragma unroll
    for (int j = 0; j < 32; ++j) buf[j] = f2h(tile[h * 32 + j][xpos]);
    u16* dst = xh + (((size_t)b * 128 + y) * 128 + xpos) * 256 + g * 64 + h * 32;
#pragma unroll
    for (int q = 0; q < 4; ++q)
        *(int4*)(dst + q * 8) = *(int4*)(buf + q * 8);
}

// ---------------- offset conv as MFMA GEMM + fused tap generation ----------------
__global__ __launch_bounds__(256) void offconv_mfma(
    const u16* __restrict__ xh, const u16* __restrict__ wboff,
    float* __restrict__ off, int4* __restrict__ tap)
{
    __shared__ __align__(16) char smem[57728];
    u16* xrowU = (u16*)smem;
    u16* bU    = (u16*)(smem + 49536);

    int blk = blockIdx.x;
    blk = (blk & 7) * 64 + (blk >> 3);   // XCD swizzle
    int b = blk >> 6, ho = blk & 63;
    int t = threadIdx.x;
    int lane = t & 63, w = t >> 6;
    int r = lane & 15, kg = lane >> 4;

    const u16* xB = xh + (size_t)b * (128 * 128 * 256);

    f32x4 acc[2];
    acc[0] = f32x4{0.f, 0.f, 0.f, 0.f};
    acc[1] = f32x4{0.f, 0.f, 0.f, 0.f};

    if (t < 24) {
        int ry = t >> 3, s = t & 7;
        *(int4*)(smem + (ry * 129 * 8 + s) * 16) = int4{0, 0, 0, 0};
    }

    for (int ch = 0; ch < 4; ++ch) {
        __syncthreads();
        for (int ry = 0; ry < 3; ++ry) {
            int y = 2 * ho - 1 + ry;
            int rowbase = (ry * 129 + 1) * 128;
            if ((unsigned)y < 128u) {
#pragma unroll
                for (int p = 0; p < 4; ++p) {
                    int u = p * 256 + t;
                    int xpi = u >> 3, s = u & 7;
                    int c8 = s ^ (((xpi + 1) >> 1) & 7);
                    gld16(xB + ((size_t)(y * 128 + xpi)) * 256 + ch * 64 + c8 * 8,
                          smem + rowbase + p * 4096 + w * 1024);
                }
            } else if (ch == 0) {
#pragma unroll
                for (int p = 0; p < 4; ++p)
                    *(int4*)(smem + rowbase + (p * 256 + t) * 16) = int4{0, 0, 0, 0};
            }
        }
        gld16(wboff + (size_t)(0 * 4 + ch) * 2048 + t * 8,
              smem + 49536 + w * 1024);
        __syncthreads();

        for (int k = 0; k < 9; ++k) {
            int buf = k & 1;
            if (k < 8)
                gld16(wboff + (size_t)((k + 1) * 4 + ch) * 2048 + t * 8,
                      smem + 49536 + (buf ^ 1) * 4096 + w * 1024);
            int ky = k / 3, kx = k - 3 * ky;
            int pixA = w * 16 + r;
            int xp = 2 * pixA + kx;
            int abase = (ky * 129 + xp) * 64;
            int swA = (xp >> 1) & 7;
#pragma unroll
            for (int ksub = 0; ksub < 2; ++ksub) {
                int lc = ksub * 4 + kg;
                h16x8 a = *(h16x8*)(xrowU + abase + ((lc ^ swA) << 3));
#pragma unroll
                for (int n = 0; n < 2; ++n) {
                    int co = n * 16 + r;
                    h16x8 bb = *(h16x8*)(bU + buf * 2048 + co * 64 +
                                         ((lc ^ ((co >> 1) & 7)) << 3));
                    acc[n] = __builtin_amdgcn_mfma_f32_16x16x32_f16(a, bb, acc[n], 0, 0, 0);
                }
            }
            __syncthreads();
        }
    }

    // epilogue: write off (global) + offL (LDS, for fused tap generation)
    float* offL = (float*)smem;   // [18][64] f32 (xrow region dead)
#pragma unroll
    for (int n = 0; n < 2; ++n) {
        int co = n * 16 + r;
        if (co < 18) {
#pragma unroll
            for (int j = 0; j < 4; ++j) {
                int wo = w * 16 + kg * 4 + j;
                float v = acc[n][j];
                off[(((size_t)b * 18 + co) * 64 + ho) * 64 + wo] = v;
                offL[co * 64 + wo] = v;
            }
        }
    }
    if (tap) {
        __syncthreads();
        for (int i = t; i < 576; i += 256) {
            int pix = i / 9, k = i - 9 * (i / 9);
            int ky = k / 3, kx = k - 3 * ky;
            float dy = offL[(2 * k) * 64 + pix];
            float dx = offL[(2 * k + 1) * 64 + pix];
            float py = (float)(ho * 2 - 1 + ky) + dy;
            float px = (float)(pix * 2 - 1 + kx) + dx;
            float y0f = floorf(py), x0f = floorf(px);
            int y0 = (int)y0f, x0i = (int)x0f;
            float wy1 = py - y0f, wx1 = px - x0f;
            float wy0 = 1.f - wy1, wx0 = 1.f - wx1;
            int y1i = y0 + 1, x1i = x0i + 1;
            bool vy0 = (unsigned)y0  < 128u;
            bool vy1 = (unsigned)y1i < 128u;
            bool vx0 = (unsigned)x0i < 128u;
            bool vx1 = (unsigned)x1i < 128u;
            int yc0 = min(max(y0, 0), 127), yc1 = min(max(y1i, 0), 127);
            int xc0 = min(max(x0i, 0), 127), xc1 = min(max(x1i, 0), 127);
            int4 e;
            e.x = (yc0 * 128 + xc0) * 512 | (xc1 - xc0) | ((yc1 - yc0) << 1);
            e.y = (int)((unsigned)f2h((vy0 && vx0) ? wy0 * wx0 : 0.f) |
                        ((unsigned)f2h((vy0 && vx1) ? wy0 * wx1 : 0.f) << 16));
            e.z = (int)((unsigned)f2h((vy1 && vx0) ? wy1 * wx0 : 0.f) |
                        ((unsigned)f2h((vy1 && vx1) ? wy1 * wx1 : 0.f) << 16));
            e.w = 0;
            tap[(size_t)(b * 64 + ho) * 576 + i] = e;
        }
    }
}

// ---------------- FUSED deform + leaky + 1x1 conv: reg-dbuf weights, sbuf-only LDS ----------------
// Part A (36 phases): B-fragments global->VGPR double-buffered one phase ahead (wA/wB);
// LDS traffic per phase = af reads + sample write only (was + 64KB wstage + 64KB bfr).
// LDS: sbuf[2] @0/@8192 (16 KB) in Part A; Part B: B-tile @0..32K, outT @32768 (64 KB total).
__global__ __launch_bounds__(512, 4) void deform_fused(
    const u16* __restrict__ xh, const int4* __restrict__ tap,
    const u16* __restrict__ wdefh, const u16* __restrict__ w1h,
    float* __restrict__ out)
{
    extern __shared__ __align__(16) char smem[];

    int blk = blockIdx.x;
    blk = (blk & 7) * 64 + (blk >> 3);       // XCD swizzle
    int b = blk >> 6, ho = blk & 63;
    int t = threadIdx.x;
    int lane = t & 63, w = t >> 6;           // 8 waves
    int r = lane & 15, kg = lane >> 4;
    int pixS = w * 8 + (lane >> 3);          // sampling pixel (8 per wave)
    int cs   = lane & 7;                     // channel slice (8 ch)

    f32x4 acc[4][2];
    f32x4 zz = {0.f, 0.f, 0.f, 0.f};
#pragma unroll
    for (int m = 0; m < 4; ++m)
#pragma unroll
        for (int n = 0; n < 2; ++n) acc[m][n] = zz;

    const int4* tapB = tap + (size_t)(b * 64 + ho) * 576 + pixS * 9;
    const char* xb2  = (const char*)(xh + (size_t)b * (128 * 128 * 256)) + cs * 16;
    // per-lane weight fragment base: row co = w*32 + r, k-slice base kg*8
    const u16* wlane = wdefh + (size_t)(w * 32 + r) * 256 + kg * 8;

    int sbw = pixS * 128 + ((cs ^ (pixS & 7)) << 4);   // sample write byte offset

    // load phase-p B-fragments into named reg buffer (static indices only)
    auto loadW = [&](int p, h16x8 (&dst)[2][2]) {
        int ch = p / 9, k = p - 9 * ch;
        const u16* wp = wlane + ((size_t)k << 16) + ch * 64;
#pragma unroll
        for (int ks = 0; ks < 2; ++ks)
#pragma unroll
            for (int n = 0; n < 2; ++n)
                dst[ks][n] = *(const h16x8*)(wp + n * 16 * 256 + ks * 32);
    };

    auto mfmaPhase = [&](h16x8 (&wreg)[2][2], char* sbc) {
        u16* sb = (u16*)sbc;
        h16x8 af[4];
        __builtin_amdgcn_s_setprio(1);
#pragma unroll
        for (int ks = 0; ks < 2; ++ks) {
            int so = ((ks * 4 + kg) ^ (r & 7)) << 3;   // u16 units
#pragma unroll
            for (int m = 0; m < 4; ++m)
                af[m] = *(h16x8*)(sb + (m * 16 + r) * 64 + so);
#pragma unroll
            for (int m = 0; m < 4; ++m)
#pragma unroll
                for (int n = 0; n < 2; ++n)
                    acc[m][n] = __builtin_amdgcn_mfma_f32_16x16x32_f16(af[m], wreg[ks][n], acc[m][n], 0, 0, 0);
        }
        __builtin_amdgcn_s_setprio(0);
    };

    h16x8 wA[2][2], wB[2][2];

    // ---- prologue: phase 0 = (ch=0, k=0): gathers + blend + weights ----
    {
        int4 e = tapB[0];
        int o00 = e.x & 0x7FFFFE00;
        int dxo = (e.x & 1) << 9;
        int dyo = (e.x & 2) << 15;
        h16x8 c00 = *(const h16x8*)(xb2 + o00);
        h16x8 c01 = *(const h16x8*)(xb2 + o00 + dxo);
        h16x8 c10 = *(const h16x8*)(xb2 + o00 + dyo);
        h16x8 c11 = *(const h16x8*)(xb2 + o00 + dyo + dxo);
        loadW(0, wA);
        union U { int u; _Float16 h[2]; };
        U u01, u23;
        u01.u = e.y; u23.u = e.z;
        h16x8 v = c00 * u01.h[0] + c01 * u01.h[1] + c10 * u23.h[0] + c11 * u23.h[1];
        *(h16x8*)(smem + sbw) = v;
    }
    __syncthreads();

    // 36 phases, 2 per iteration: static wA/wB + sbuf0/sbuf1 indexing
    for (int pp = 0; pp < 36; pp += 2) {
        // even phase pp: consumes wA + sbuf0; prefetch pp+1 (gathers first, weights second)
        {
            int pn = pp + 1;
            int kn = pn - 9 * (pn / 9), chn = pn / 9;
            int4 e = tapB[kn];
            int o00 = e.x & 0x7FFFFE00;
            int dxo = (e.x & 1) << 9;
            int dyo = (e.x & 2) << 15;
            const char* base = xb2 + chn * 128;
            h16x8 c00 = *(const h16x8*)(base + o00);
            h16x8 c01 = *(const h16x8*)(base + o00 + dxo);
            h16x8 c10 = *(const h16x8*)(base + o00 + dyo);
            h16x8 c11 = *(const h16x8*)(base + o00 + dyo + dxo);
            loadW(pn, wB);
            mfmaPhase(wA, smem);               // covers gather+weight latency
            union U { int u; _Float16 h[2]; };
            U u01, u23;
            u01.u = e.y; u23.u = e.z;
            h16x8 v = c00 * u01.h[0] + c01 * u01.h[1] + c10 * u23.h[0] + c11 * u23.h[1];
            *(h16x8*)(smem + 8192 + sbw) = v;
        }
        __syncthreads();
        // odd phase pp+1: consumes wB + sbuf1; prefetch pp+2 into wA + sbuf0
        if (pp + 2 < 36) {
            int pn = pp + 2;
            int kn = pn - 9 * (pn / 9), chn = pn / 9;
            int4 e = tapB[kn];
            int o00 = e.x & 0x7FFFFE00;
            int dxo = (e.x & 1) << 9;
            int dyo = (e.x & 2) << 15;
            const char* base = xb2 + chn * 128;
            h16x8 c00 = *(const h16x8*)(base + o00);
            h16x8 c01 = *(const h16x8*)(base + o00 + dxo);
            h16x8 c10 = *(const h16x8*)(base + o00 + dyo);
            h16x8 c11 = *(const h16x8*)(base + o00 + dyo + dxo);
            loadW(pn, wA);
            mfmaPhase(wB, smem + 8192);
            union U { int u; _Float16 h[2]; };
            U u01, u23;
            u01.u = e.y; u23.u = e.z;
            h16x8 v = c00 * u01.h[0] + c01 * u01.h[1] + c10 * u23.h[0] + c11 * u23.h[1];
            *(h16x8*)(smem + sbw) = v;
        } else {
            mfmaPhase(wB, smem + 8192);
        }
        __syncthreads();
    }

    // ---- Part B: leaky + tile to LDS (outT @32768, XOR-swizzled), 1x1 GEMM, out ----
    char* outT = smem + 32768;   // [64 pix][256 co] fp16, byte = prow*512 + ((co*2)^((prow&7)<<4))
    int rg = lane >> 4;
#pragma unroll
    for (int m = 0; m < 4; ++m)
#pragma unroll
        for (int n = 0; n < 2; ++n) {
            int co = w * 32 + n * 16 + r;
#pragma unroll
            for (int j = 0; j < 4; ++j) {
                int prow = m * 16 + rg * 4 + j;
                *(u16*)(outT + prow * 512 + ((co * 2) ^ ((prow & 7) << 4))) =
                    f2h(lrelu(acc[m][n][j]));
            }
        }

    // B-tile stage for ch2: [256 o][64 c] = 32KB into [0,32K), conflict-free swizzle
    auto stage1 = [&](int ch2) {
#pragma unroll
        for (int p2 = 0; p2 < 4; ++p2) {
            int i = p2 * 512 + t;
            int o = i >> 3, s = i & 7;
            gld16(w1h + (size_t)o * 256 + ch2 * 64 + ((s ^ (o & 7)) << 3),
                  smem + p2 * 8192 + w * 1024);
        }
    };

    stage1(0);                 // issue alongside outT writes
#pragma unroll
    for (int m = 0; m < 4; ++m)
#pragma unroll
        for (int n = 0; n < 2; ++n) acc[m][n] = zz;
    __syncthreads();           // drains outT writes + B stage

    for (int ch2 = 0; ch2 < 4; ++ch2) {
        h16x8 af[4], bfr[2];
        __builtin_amdgcn_s_setprio(1);
#pragma unroll
        for (int ksub = 0; ksub < 2; ++ksub) {
            int cb = (ch2 * 64 + (ksub * 4 + kg) * 8) * 2;
#pragma unroll
            for (int m = 0; m < 4; ++m) {
                int prow = m * 16 + r;
                af[m] = *(h16x8*)(outT + prow * 512 + (cb ^ ((prow & 7) << 4)));
            }
#pragma unroll
            for (int n = 0; n < 2; ++n) {
                int o = w * 32 + n * 16 + r;
                bfr[n] = *(h16x8*)(smem + o * 128 + (((ksub * 4 + kg) ^ (o & 7)) << 4));
            }
#pragma unroll
            for (int m = 0; m < 4; ++m)
#pragma unroll
                for (int n = 0; n < 2; ++n)
                    acc[m][n] = __builtin_amdgcn_mfma_f32_16x16x32_f16(af[m], bfr[n], acc[m][n], 0, 0, 0);
        }
        __builtin_amdgcn_s_setprio(0);
        __syncthreads();
        if (ch2 < 3) {
            stage1(ch2 + 1);
            __syncthreads();
        }
    }

    // write pre-norm result to d_out: out[b][o][ho][pix]
#pragma unroll
    for (int m = 0; m < 4; ++m)
#pragma unroll
        for (int n = 0; n < 2; ++n) {
            int o = w * 32 + n * 16 + r;
            int pix0 = m * 16 + rg * 4;
            float4 v;
            v.x = acc[m][n][0]; v.y = acc[m][n][1];
            v.z = acc[m][n][2]; v.w = acc[m][n][3];
            *(float4*)(out + ((size_t)(b * 256 + o) * 64 + ho) * 64 + pix0) = v;
        }
}

// ---------------- deformable conv (fallback): inline coords -> y1p ----------------
__global__ __launch_bounds__(512, 4) void deform_inline(
    const u16* __restrict__ xh, const float* __restrict__ off,
    const u16* __restrict__ wdefh, u16* __restrict__ y1p)
{
    extern __shared__ __align__(16) char smem[];

    int blk = blockIdx.x;
    blk = (blk & 7) * 64 + (blk >> 3);
    int b = blk >> 6, ho = blk & 63;
    int t = threadIdx.x;
    int lane = t & 63, w = t >> 6;
    int r = lane & 15, kg = lane >> 4;
    int pixS = w * 8 + (lane >> 3);
    int cs   = lane & 7;

    f32x4 acc[4][2];
    f32x4 zz = {0.f, 0.f, 0.f, 0.f};
#pragma unroll
    for (int m = 0; m < 4; ++m)
#pragma unroll
        for (int n = 0; n < 2; ++n) acc[m][n] = zz;

    const u16* xB = xh + (size_t)b * (128 * 128 * 256);

    int o00, o01, o10, o11;
    float f00, f01, f10, f11;

    auto coords = [&](int k) {
        int ky = k / 3, kx = k - 3 * ky;
        float dy = off[(((size_t)b * 18 + 2 * k    ) * 64 + ho) * 64 + pixS];
        float dx = off[(((size_t)b * 18 + 2 * k + 1) * 64 + ho) * 64 + pixS];
        float py = (float)(ho * 2 - 1 + ky) + dy;
        float px = (float)(pixS * 2 - 1 + kx) + dx;
        float y0f = floorf(py), x0f = floorf(px);
        int y0 = (int)y0f, x0i = (int)x0f;
        float wy1 = py - y0f, wx1 = px - x0f;
        float wy0 = 1.f - wy1, wx0 = 1.f - wx1;
        int y1i = y0 + 1, x1i = x0i + 1;
        bool vy0 = (unsigned)y0  < 128u;
        bool vy1 = (unsigned)y1i < 128u;
        bool vx0 = (unsigned)x0i < 128u;
        bool vx1 = (unsigned)x1i < 128u;
        int yc0 = min(max(y0, 0), 127), yc1 = min(max(y1i, 0), 127);
        int xc0 = min(max(x0i, 0), 127), xc1 = min(max(x1i, 0), 127);
        o00 = yc0 * 128 + xc0;  o01 = yc0 * 128 + xc1;
        o10 = yc1 * 128 + xc0;  o11 = yc1 * 128 + xc1;
        f00 = (vy0 && vx0) ? wy0 * wx0 : 0.f;
        f01 = (vy0 && vx1) ? wy0 * wx1 : 0.f;
        f10 = (vy1 && vx0) ? wy1 * wx0 : 0.f;
        f11 = (vy1 && vx1) ? wy1 * wx1 : 0.f;
    };

    auto stage = [&](int k, int ch, int dbuf) {
        const u16* wk = wdefh + ((size_t)k << 16);
#pragma unroll
        for (int p2 = 0; p2 < 4; ++p2) {
            int i = p2 * 512 + t;
            int co = i >> 3, s = i & 7;
            gld16(wk + (size_t)co * 256 + ch * 64 + ((s ^ (co & 7)) << 3),
                  smem + dbuf * 32768 + p2 * 8192 + w * 1024);
        }
    };

    auto sample = [&](int ch, int dbuf) {
        int cw = ch * 64 + cs * 8;
        const u16* q00 = xB + (size_t)o00 * 256 + cw;
        const u16* q01 = xB + (size_t)o01 * 256 + cw;
        const u16* q10 = xB + (size_t)o10 * 256 + cw;
        const u16* q11 = xB + (size_t)o11 * 256 + cw;
        h16x8 c00 = *(const h16x8*)q00;
        h16x8 c01 = *(const h16x8*)q01;
        h16x8 c10 = *(const h16x8*)q10;
        h16x8 c11 = *(const h16x8*)q11;
        _Float16 hf00 = (_Float16)f00, hf01 = (_Float16)f01;
        _Float16 hf10 = (_Float16)f10, hf11 = (_Float16)f11;
        h16x8 v = c00 * hf00 + c01 * hf01 + c10 * hf10 + c11 * hf11;
        *(h16x8*)(smem + 65536 + dbuf * 8192 + pixS * 128 + ((cs ^ (pixS & 7)) << 4)) = v;
    };

    coords(0);
    stage(0, 0, 0);
    sample(0, 0);
    __syncthreads();

    for (int p = 0; p < 36; ++p) {
        int cur = p & 1;
        if (p < 35) {
            int pn = p + 1;
            int chn = pn / 9, kn = pn - 9 * chn;
            stage(kn, chn, cur ^ 1);
            coords(kn);
            sample(chn, cur ^ 1);
        }
        u16* wb = (u16*)(smem + cur * 32768);
        u16* sb = (u16*)(smem + 65536 + cur * 8192);
        h16x8 af[4], bfr[2];
        __builtin_amdgcn_s_setprio(1);
#pragma unroll
        for (int ksub = 0; ksub < 2; ++ksub) {
            int so = ((ksub * 4 + kg) ^ (r & 7)) << 3;
#pragma unroll
            for (int m = 0; m < 4; ++m)
                af[m] = *(h16x8*)(sb + (m * 16 + r) * 64 + so);
#pragma unroll
            for (int n = 0; n < 2; ++n)
                bfr[n] = *(h16x8*)(wb + (w * 32 + n * 16 + r) * 64 + so);
#pragma unroll
            for (int m = 0; m < 4; ++m)
#pragma unroll
                for (int n = 0; n < 2; ++n)
                    acc[m][n] = __builtin_amdgcn_mfma_f32_16x16x32_f16(af[m], bfr[n], acc[m][n], 0, 0, 0);
        }
        __builtin_amdgcn_s_setprio(0);
        __syncthreads();
    }

    u16* outT = (u16*)smem;
    int rg = lane >> 4;
#pragma unroll
    for (int m = 0; m < 4; ++m)
#pragma unroll
        for (int n = 0; n < 2; ++n) {
            int co = w * 32 + n * 16 + r;
#pragma unroll
            for (int j = 0; j < 4; ++j) {
                int prow = m * 16 + rg * 4 + j;
                outT[prow * 256 + co] = f2h(lrelu(acc[m][n][j]));
            }
        }
    __syncthreads();
    u16* dst = y1p + (size_t)(b * 64 + ho) * 16384;
#pragma unroll
    for (int p = 0; p < 4; ++p)
        *(int4*)((char*)dst + p * 8192 + t * 16) = *(int4*)(smem + p * 8192 + t * 16);
}

// ---------------- 1x1 conv: fp16 MFMA (fallback path only) ----------------
__global__ __launch_bounds__(256) void conv1x1_mfma(
    const u16* __restrict__ y1p, const u16* __restrict__ w1h,
    float* __restrict__ out)
{
    __shared__ __align__(16) char smem[20480];
    u16* btile = (u16*)smem;
    u16* atile = (u16*)(smem + 16384);

    int blk = blockIdx.x;
    blk = (blk & 7) * 64 + (blk >> 3);
    int b = blk >> 6, ho = blk & 63;
    int t = threadIdx.x, lane = t & 63, w = t >> 6;
    int r = lane & 15, kg = lane >> 4;
    int sR = (r >> 1) & 3;

    f32x4 acc[4][4];
    f32x4 zz = {0.f, 0.f, 0.f, 0.f};
#pragma unroll
    for (int m = 0; m < 4; ++m)
#pragma unroll
        for (int n = 0; n < 4; ++n) acc[m][n] = zz;

    const u16* abase = y1p + (size_t)(b * 64 + ho) * 16384;

    for (int ch = 0; ch < 8; ++ch) {
#pragma unroll
        for (int p = 0; p < 4; ++p) {
            int slot = p * 256 + t;
            int o = slot >> 2, qq = slot & 3;
            gld16(w1h + o * 256 + ch * 32 + ((qq ^ ((o >> 1) & 3)) << 3),
                  smem + p * 4096 + (t >> 6) * 1024);
        }
        {
            int pix = t >> 2, qq = t & 3;
            gld16(abase + pix * 256 + ch * 32 + ((qq ^ ((pix >> 1) & 3)) << 3),
                  smem + 16384 + (t >> 6) * 1024);
        }
        __syncthreads();
        h16x8 af[4], bfr[4];
#pragma unroll
        for (int m = 0; m < 4; ++m)
            af[m] = *(h16x8*)(atile + (m * 16 + r) * 32 + ((kg ^ sR) << 3));
#pragma unroll
        for (int n = 0; n < 4; ++n)
            bfr[n] = *(h16x8*)(btile + (w * 64 + n * 16 + r) * 32 + ((kg ^ sR) << 3));
#pragma unroll
        for (int m = 0; m < 4; ++m)
#pragma unroll
            for (int n = 0; n < 4; ++n)
                acc[m][n] = __builtin_amdgcn_mfma_f32_16x16x32_f16(af[m], bfr[n], acc[m][n], 0, 0, 0);
        __syncthreads();
    }

    int rg = lane >> 4;
#pragma unroll
    for (int m = 0; m < 4; ++m)
#pragma unroll
        for (int n = 0; n < 4; ++n) {
            int o = w * 64 + n * 16 + r;
            int pix0 = m * 16 + rg * 4;
            float4 v;
            v.x = acc[m][n][0]; v.y = acc[m][n][1];
            v.z = acc[m][n][2]; v.w = acc[m][n][3];
            *(float4*)(out + ((size_t)(b * 256 + o) * 64 + ho) * 64 + pix0) = v;
        }
}

// ---------------- instance norm + leaky, in place on d_out ----------------
__global__ __launch_bounds__(256) void instnorm(float* __restrict__ out)
{
    int bc = blockIdx.x;
    float* p = out + (size_t)bc * 4096;
    int t = threadIdx.x;

    float4 v[4];
    float s1 = 0.f, s2 = 0.f;
#pragma unroll
    for (int i = 0; i < 4; ++i) {
        v[i] = *(const float4*)&p[(t + i * 256) * 4];
        s1 += v[i].x + v[i].y + v[i].z + v[i].w;
        s2 += v[i].x * v[i].x + v[i].y * v[i].y + v[i].z * v[i].z + v[i].w * v[i].w;
    }
#pragma unroll
    for (int o = 32; o > 0; o >>= 1) {
        s1 += __shfl_down(s1, o);
        s2 += __shfl_down(s2, o);
    }
    __shared__ float rs[8];
    __shared__ float mb[2];
    int wave = t >> 6;
    if ((t & 63) == 0) { rs[wave] = s1; rs[4 + wave] = s2; }
    __syncthreads();
    if (t == 0) {
        float a = rs[0] + rs[1] + rs[2] + rs[3];
        float qq = rs[4] + rs[5] + rs[6] + rs[7];
        float mean = a * (1.f / 4096.f);
        float var  = qq * (1.f / 4096.f) - mean * mean;
        mb[0] = mean;
        mb[1] = rsqrtf(var + 1e-5f);
    }
    __syncthreads();
    float mean = mb[0], inv = mb[1];
#pragma unroll
    for (int i = 0; i < 4; ++i) {
        float4 u = v[i];
        u.x = lrelu((u.x - mean) * inv);
        u.y = lrelu((u.y - mean) * inv);
        u.z = lrelu((u.z - mean) * inv);
        u.w = lrelu((u.w - mean) * inv);
        *(float4*)&p[(t + i * 256) * 4] = u;
    }
}

extern "C" void kernel_launch(void* const* d_in, const int* in_sizes, int n_in,
                              void* d_out, int out_size, void* d_ws, size_t ws_size,
                              hipStream_t stream)
{
    const float* x     = (const float*)d_in[0];
    const float* w_off = (const float*)d_in[1];
    const float* w_def = (const float*)d_in[2];
    const float* w1    = (const float*)d_in[3];
    float* out = (float*)d_out;
    float* ws  = (float*)d_ws;

    float* off   = ws + OFF_OFS;
    u16*   wdefh = (u16*)(ws + WDEF_OFS);
    u16*   w1h   = (u16*)(ws + W1_OFS);
    u16*   wboff = (u16*)(ws + WBOFF_OFS);
    u16*   y1p   = (u16*)(ws + Y1_OFS);
    u16*   xh    = (u16*)(ws + XBF_OFS);
    int4*  tap   = (int4*)(ws + TAP_OFS);

    const bool use_tap = ws_size >= WS_NEED_TAP;   // constant per session -> deterministic

    hipFuncSetAttribute((const void*)deform_fused,
                        hipFuncAttributeMaxDynamicSharedMemorySize, 65536);
    hipFuncSetAttribute((const void*)deform_inline,
                        hipFuncAttributeMaxDynamicSharedMemorySize, 81920);

    hipLaunchKernelGGL(prep,         dim3(2304), dim3(256), 0, stream, w_def, w1, w_off, wdefh, w1h, wboff);
    hipLaunchKernelGGL(nchw2nhwc,    dim3(4096), dim3(256), 0, stream, x, xh);
    hipLaunchKernelGGL(offconv_mfma, dim3(512),  dim3(256), 0, stream, xh, wboff, off,
                       use_tap ? tap : (int4*)nullptr);
    if (use_tap) {
        hipLaunchKernelGGL(deform_fused, dim3(512), dim3(512), 65536, stream, xh, tap, wdefh, w1h, out);
    } else {
        hipLaunchKernelGGL(deform_inline, dim3(512), dim3(512), 81920, stream, xh, off, wdefh, y1p);
        hipLaunchKernelGGL(conv1x1_mfma,  dim3(512), dim3(256), 0, stream, y1p, w1h, out);
    }
    hipLaunchKernelGGL(instnorm,     dim3(2048), dim3(256), 0, stream, out);
}

// Round 24
// 144.699 us; speedup vs baseline: 1.2317x; 1.2317x over previous
//
#include <hip/hip_runtime.h>

#define B_   8
#define CIN  256
#define H_   128
#define W_   128
#define HO   64
#define WO   64
#define CO_  256
#define NEG  0.2f

typedef __attribute__((ext_vector_type(8))) _Float16 h16x8;
typedef __attribute__((ext_vector_type(4))) float f32x4;
typedef unsigned short u16;

// ws layout (float slots):
//  off    : [8][18][64][64] f32            @ 0         (589824)
//  wdefh  : [9][256][256] fp16             @ 589824    (294912 slots)
//  w1h    : [256][256] fp16                @ 884736    (32768 slots)
//  wboff  : [9][4][32][64] fp16 pre-swz    @ 917504    (36864 slots)
//  y1p    : [8][64][64][256] fp16          @ 954368    (4194304 slots) -- fallback path only
//  xh     : [8][128][128][256] fp16        @ 5148672   (16777216 slots = 64 MB)
//  tap    : [8][64][64][9] x 16B           @ 21925888  (1179648 slots) -- ONLY if ws fits
#define OFF_OFS   0
#define WDEF_OFS  589824
#define W1_OFS    884736
#define WBOFF_OFS 917504
#define Y1_OFS    954368
#define XBF_OFS   5148672
#define TAP_OFS   21925888
#define WS_NEED_TAP ((21925888ull + 1179648ull) * 4ull)   // 92.4 MB

__device__ __forceinline__ float lrelu(float v) { return v >= 0.f ? v : NEG * v; }

__device__ __forceinline__ u16 f2h(float f) {
    _Float16 h = (_Float16)f;           // v_cvt_f16_f32 (RNE)
    return *(u16*)&h;
}

__device__ __forceinline__ void gld16(const void* g, void* l) {
    __builtin_amdgcn_global_load_lds((const __attribute__((address_space(1))) unsigned*)g,
                                     (__attribute__((address_space(3))) unsigned*)l, 16, 0, 0);
}

// ---------------- one-time weight prep (fp16) ----------------
__global__ __launch_bounds__(256) void prep(
    const float* __restrict__ wdef, const float* __restrict__ w1,
    const float* __restrict__ woff,
    u16* __restrict__ wdefh, u16* __restrict__ w1h, u16* __restrict__ wboff)
{
    int i = blockIdx.x * 256 + threadIdx.x;
    if (i < 9 * 256 * 256) {
        int c  = i & 255;
        int co = (i >> 8) & 255;
        int k  = i >> 16;
        wdefh[i] = f2h(wdef[((size_t)co * 256 + c) * 9 + k]);
    }
    if (i < 65536) w1h[i] = f2h(w1[i]);
    if (i < 73728) {
        int j  = i & 7;
        int s  = (i >> 3) & 7;
        int co = (i >> 6) & 31;
        int ch = (i >> 11) & 3;
        int k  = i >> 13;
        int c  = ch * 64 + ((s ^ ((co >> 1) & 7)) << 3) + j;
        wboff[i] = (co < 18) ? f2h(woff[((size_t)co * 256 + c) * 9 + k]) : (u16)0;
    }
}

// ---------------- x: NCHW fp32 -> NHWC fp16 (one-time) ----------------
__global__ __launch_bounds__(256) void nchw2nhwc(
    const float* __restrict__ x, u16* __restrict__ xh)
{
    __shared__ float tile[64][128];   // 32 KB
    int bid = blockIdx.x;
    int g = bid & 3;
    int y = (bid >> 2) & 127;
    int b = bid >> 9;
    int t = threadIdx.x;

    const float* src = x + ((size_t)(b * 256 + g * 64) * 128 + y) * 128;
#pragma unroll
    for (int p = 0; p < 8; ++p) {
        int i = p * 256 + t;
        int cc = i >> 5, x4 = (i & 31) * 4;
        *(float4*)&tile[cc][x4] = *(const float4*)(src + (size_t)cc * 16384 + x4);
    }
    __syncthreads();

    int xpos = t >> 1, h = t & 1;
    u16 buf[32];
#pragma unroll
    for (int j = 0; j < 32; ++j) buf[j] = f2h(tile[h * 32 + j][xpos]);
    u16* dst = xh + (((size_t)b * 128 + y) * 128 + xpos) * 256 + g * 64 + h * 32;
#pragma unroll
    for (int q = 0; q < 4; ++q)
        *(int4*)(dst + q * 8) = *(int4*)(buf + q * 8);
}

// ---------------- offset conv as MFMA GEMM + fused tap generation ----------------
// If tap != nullptr, the epilogue also emits the 16B tap entries for this (b,ho)
// from the register-resident off tile via LDS (saves the tapgen launch + off re-read).
__global__ __launch_bounds__(256) void offconv_mfma(
    const u16* __restrict__ xh, const u16* __restrict__ wboff,
    float* __restrict__ off, int4* __restrict__ tap)
{
    __shared__ __align__(16) char smem[57728];
    u16* xrowU = (u16*)smem;
    u16* bU    = (u16*)(smem + 49536);

    int blk = blockIdx.x;
    blk = (blk & 7) * 64 + (blk >> 3);   // XCD swizzle
    int b = blk >> 6, ho = blk & 63;
    int t = threadIdx.x;
    int lane = t & 63, w = t >> 6;
    int r = lane & 15, kg = lane >> 4;

    const u16* xB = xh + (size_t)b * (128 * 128 * 256);

    f32x4 acc[2];
    acc[0] = f32x4{0.f, 0.f, 0.f, 0.f};
    acc[1] = f32x4{0.f, 0.f, 0.f, 0.f};

    if (t < 24) {
        int ry = t >> 3, s = t & 7;
        *(int4*)(smem + (ry * 129 * 8 + s) * 16) = int4{0, 0, 0, 0};
    }

    for (int ch = 0; ch < 4; ++ch) {
        __syncthreads();
        for (int ry = 0; ry < 3; ++ry) {
            int y = 2 * ho - 1 + ry;
            int rowbase = (ry * 129 + 1) * 128;
            if ((unsigned)y < 128u) {
#pragma unroll
                for (int p = 0; p < 4; ++p) {
                    int u = p * 256 + t;
                    int xpi = u >> 3, s = u & 7;
                    int c8 = s ^ (((xpi + 1) >> 1) & 7);
                    gld16(xB + ((size_t)(y * 128 + xpi)) * 256 + ch * 64 + c8 * 8,
                          smem + rowbase + p * 4096 + w * 1024);
                }
            } else if (ch == 0) {
#pragma unroll
                for (int p = 0; p < 4; ++p)
                    *(int4*)(smem + rowbase + (p * 256 + t) * 16) = int4{0, 0, 0, 0};
            }
        }
        gld16(wboff + (size_t)(0 * 4 + ch) * 2048 + t * 8,
              smem + 49536 + w * 1024);
        __syncthreads();

        for (int k = 0; k < 9; ++k) {
            int buf = k & 1;
            if (k < 8)
                gld16(wboff + (size_t)((k + 1) * 4 + ch) * 2048 + t * 8,
                      smem + 49536 + (buf ^ 1) * 4096 + w * 1024);
            int ky = k / 3, kx = k - 3 * ky;
            int pixA = w * 16 + r;
            int xp = 2 * pixA + kx;
            int abase = (ky * 129 + xp) * 64;
            int swA = (xp >> 1) & 7;
#pragma unroll
            for (int ksub = 0; ksub < 2; ++ksub) {
                int lc = ksub * 4 + kg;
                h16x8 a = *(h16x8*)(xrowU + abase + ((lc ^ swA) << 3));
#pragma unroll
                for (int n = 0; n < 2; ++n) {
                    int co = n * 16 + r;
                    h16x8 bb = *(h16x8*)(bU + buf * 2048 + co * 64 +
                                         ((lc ^ ((co >> 1) & 7)) << 3));
                    acc[n] = __builtin_amdgcn_mfma_f32_16x16x32_f16(a, bb, acc[n], 0, 0, 0);
                }
            }
            __syncthreads();
        }
    }

    // epilogue: write off (global) + offL (LDS, for fused tap generation)
    float* offL = (float*)smem;   // [18][64] f32 = 4.6 KB (xrow region dead)
#pragma unroll
    for (int n = 0; n < 2; ++n) {
        int co = n * 16 + r;
        if (co < 18) {
#pragma unroll
            for (int j = 0; j < 4; ++j) {
                int wo = w * 16 + kg * 4 + j;
                float v = acc[n][j];
                off[(((size_t)b * 18 + co) * 64 + ho) * 64 + wo] = v;
                offL[co * 64 + wo] = v;
            }
        }
    }
    if (tap) {
        __syncthreads();
        for (int i = t; i < 576; i += 256) {
            int pix = i / 9, k = i - 9 * (i / 9);
            int ky = k / 3, kx = k - 3 * ky;
            float dy = offL[(2 * k) * 64 + pix];
            float dx = offL[(2 * k + 1) * 64 + pix];
            float py = (float)(ho * 2 - 1 + ky) + dy;
            float px = (float)(pix * 2 - 1 + kx) + dx;
            float y0f = floorf(py), x0f = floorf(px);
            int y0 = (int)y0f, x0i = (int)x0f;
            float wy1 = py - y0f, wx1 = px - x0f;
            float wy0 = 1.f - wy1, wx0 = 1.f - wx1;
            int y1i = y0 + 1, x1i = x0i + 1;
            bool vy0 = (unsigned)y0  < 128u;
            bool vy1 = (unsigned)y1i < 128u;
            bool vx0 = (unsigned)x0i < 128u;
            bool vx1 = (unsigned)x1i < 128u;
            int yc0 = min(max(y0, 0), 127), yc1 = min(max(y1i, 0), 127);
            int xc0 = min(max(x0i, 0), 127), xc1 = min(max(x1i, 0), 127);
            int4 e;
            e.x = (yc0 * 128 + xc0) * 512 | (xc1 - xc0) | ((yc1 - yc0) << 1);
            e.y = (int)((unsigned)f2h((vy0 && vx0) ? wy0 * wx0 : 0.f) |
                        ((unsigned)f2h((vy0 && vx1) ? wy0 * wx1 : 0.f) << 16));
            e.z = (int)((unsigned)f2h((vy1 && vx0) ? wy1 * wx0 : 0.f) |
                        ((unsigned)f2h((vy1 && vx1) ? wy1 * wx1 : 0.f) << 16));
            e.w = 0;
            tap[(size_t)(b * 64 + ho) * 576 + i] = e;
        }
    }
}

// ---------------- FUSED deformable conv + leaky + 1x1 conv (tap path) ----------------
// Part A (36 phases): T14 deform pipeline -> acc = y1 tile [64 pix][256 co].
// Part B: leaky+fp16 tile -> LDS outT (swizzled), then 4 K=64 MFMA phases vs w1h
// staged in Part A's conflict-free [256 o][64 c] layout; fp32 result to d_out.
__global__ __launch_bounds__(512, 4) void deform_fused(
    const u16* __restrict__ xh, const int4* __restrict__ tap,
    const u16* __restrict__ wdefh, const u16* __restrict__ w1h,
    float* __restrict__ out)
{
    extern __shared__ __align__(16) char smem[];

    int blk = blockIdx.x;
    blk = (blk & 7) * 64 + (blk >> 3);       // XCD swizzle
    int b = blk >> 6, ho = blk & 63;
    int t = threadIdx.x;
    int lane = t & 63, w = t >> 6;           // 8 waves
    int r = lane & 15, kg = lane >> 4;
    int pixS = w * 8 + (lane >> 3);          // sampling pixel (8 per wave)
    int cs   = lane & 7;                     // channel slice (8 ch)

    f32x4 acc[4][2];
    f32x4 zz = {0.f, 0.f, 0.f, 0.f};
#pragma unroll
    for (int m = 0; m < 4; ++m)
#pragma unroll
        for (int n = 0; n < 2; ++n) acc[m][n] = zz;

    const int4* tapB = tap + (size_t)(b * 64 + ho) * 576 + pixS * 9;
    const char* xb2  = (const char*)(xh + (size_t)b * (128 * 128 * 256)) + cs * 16;

    int sbw = pixS * 128 + ((cs ^ (pixS & 7)) << 4);   // sample write byte offset

    auto stage = [&](int k, int ch, int dbuf) {
        const u16* wk = wdefh + ((size_t)k << 16);
#pragma unroll
        for (int p2 = 0; p2 < 4; ++p2) {
            int i = p2 * 512 + t;
            int co = i >> 3, s = i & 7;
            gld16(wk + (size_t)co * 256 + ch * 64 + ((s ^ (co & 7)) << 3),
                  smem + dbuf * 32768 + p2 * 8192 + w * 1024);
        }
    };

    // ---- Part A prologue: phase 0 = (ch=0, k=0) staged+sampled synchronously ----
    {
        stage(0, 0, 0);
        int4 e = tapB[0];
        int o00 = e.x & 0x7FFFFE00;
        int dxo = (e.x & 1) << 9;
        int dyo = (e.x & 2) << 15;
        h16x8 c00 = *(const h16x8*)(xb2 + o00);
        h16x8 c01 = *(const h16x8*)(xb2 + o00 + dxo);
        h16x8 c10 = *(const h16x8*)(xb2 + o00 + dyo);
        h16x8 c11 = *(const h16x8*)(xb2 + o00 + dyo + dxo);
        union U { int u; _Float16 h[2]; };
        U u01, u23;
        u01.u = e.y; u23.u = e.z;
        h16x8 v = c00 * u01.h[0] + c01 * u01.h[1] + c10 * u23.h[0] + c11 * u23.h[1];
        *(h16x8*)(smem + 65536 + sbw) = v;
    }
    __syncthreads();

    for (int p = 0; p < 36; ++p) {
        int cur = p & 1;
        bool nx = p < 35;
        int4 e;
        h16x8 c00, c01, c10, c11;
        if (nx) {
            int pn = p + 1;
            int chn = pn / 9, kn = pn - 9 * chn;   // ch-outer, k-inner
            e = tapB[kn];
            int o00 = e.x & 0x7FFFFE00;
            int dxo = (e.x & 1) << 9;
            int dyo = (e.x & 2) << 15;
            const char* base = xb2 + chn * 128;
            c00 = *(const h16x8*)(base + o00);
            c01 = *(const h16x8*)(base + o00 + dxo);
            c10 = *(const h16x8*)(base + o00 + dyo);
            c11 = *(const h16x8*)(base + o00 + dyo + dxo);
            stage(kn, chn, cur ^ 1);
        }
        {
            u16* wb = (u16*)(smem + cur * 32768);
            u16* sb = (u16*)(smem + 65536 + cur * 8192);
            h16x8 af[4], bfr[2];
            __builtin_amdgcn_s_setprio(1);
#pragma unroll
            for (int ksub = 0; ksub < 2; ++ksub) {
                int so = ((ksub * 4 + kg) ^ (r & 7)) << 3;
#pragma unroll
                for (int m = 0; m < 4; ++m)
                    af[m] = *(h16x8*)(sb + (m * 16 + r) * 64 + so);
#pragma unroll
                for (int n = 0; n < 2; ++n)
                    bfr[n] = *(h16x8*)(wb + (w * 32 + n * 16 + r) * 64 + so);
#pragma unroll
                for (int m = 0; m < 4; ++m)
#pragma unroll
                    for (int n = 0; n < 2; ++n)
                        acc[m][n] = __builtin_amdgcn_mfma_f32_16x16x32_f16(af[m], bfr[n], acc[m][n], 0, 0, 0);
            }
            __builtin_amdgcn_s_setprio(0);
        }
        if (nx) {
            union U { int u; _Float16 h[2]; };
            U u01, u23;
            u01.u = e.y; u23.u = e.z;
            h16x8 v = c00 * u01.h[0] + c01 * u01.h[1] + c10 * u23.h[0] + c11 * u23.h[1];
            *(h16x8*)(smem + 65536 + (cur ^ 1) * 8192 + sbw) = v;
        }
        __syncthreads();
    }

    // ---- Part B: leaky + tile to LDS (outT @32768, XOR-swizzled), 1x1 GEMM, out ----
    char* outT = smem + 32768;   // [64 pix][256 co] fp16, byte = prow*512 + ((co*2)^((prow&7)<<4))
    int rg = lane >> 4;
#pragma unroll
    for (int m = 0; m < 4; ++m)
#pragma unroll
        for (int n = 0; n < 2; ++n) {
            int co = w * 32 + n * 16 + r;
#pragma unroll
            for (int j = 0; j < 4; ++j) {
                int prow = m * 16 + rg * 4 + j;
                *(u16*)(outT + prow * 512 + ((co * 2) ^ ((prow & 7) << 4))) =
                    f2h(lrelu(acc[m][n][j]));
            }
        }

    // B-tile stage for ch2: [256 o][64 c] = 32KB into wbuf0 region [0,32K), Part A swizzle
    auto stage1 = [&](int ch2) {
#pragma unroll
        for (int p2 = 0; p2 < 4; ++p2) {
            int i = p2 * 512 + t;
            int o = i >> 3, s = i & 7;
            gld16(w1h + (size_t)o * 256 + ch2 * 64 + ((s ^ (o & 7)) << 3),
                  smem + p2 * 8192 + w * 1024);
        }
    };

    stage1(0);                 // issue alongside outT writes
#pragma unroll
    for (int m = 0; m < 4; ++m)
#pragma unroll
        for (int n = 0; n < 2; ++n) acc[m][n] = zz;
    __syncthreads();           // drains outT writes + B stage

    for (int ch2 = 0; ch2 < 4; ++ch2) {
        h16x8 af[4], bfr[2];
        __builtin_amdgcn_s_setprio(1);
#pragma unroll
        for (int ksub = 0; ksub < 2; ++ksub) {
            int cb = (ch2 * 64 + (ksub * 4 + kg) * 8) * 2;   // byte offset of c-slice in outT row
#pragma unroll
            for (int m = 0; m < 4; ++m) {
                int prow = m * 16 + r;
                af[m] = *(h16x8*)(outT + prow * 512 + (cb ^ ((prow & 7) << 4)));
            }
#pragma unroll
            for (int n = 0; n < 2; ++n) {
                int o = w * 32 + n * 16 + r;
                bfr[n] = *(h16x8*)(smem + o * 128 + (((ksub * 4 + kg) ^ (o & 7)) << 4));
            }
#pragma unroll
            for (int m = 0; m < 4; ++m)
#pragma unroll
                for (int n = 0; n < 2; ++n)
                    acc[m][n] = __builtin_amdgcn_mfma_f32_16x16x32_f16(af[m], bfr[n], acc[m][n], 0, 0, 0);
        }
        __builtin_amdgcn_s_setprio(0);
        __syncthreads();       // all reads of wbuf0 done
        if (ch2 < 3) {
            stage1(ch2 + 1);
            __syncthreads();   // restage complete
        }
    }

    // write pre-norm result to d_out: out[b][o][ho][pix]
#pragma unroll
    for (int m = 0; m < 4; ++m)
#pragma unroll
        for (int n = 0; n < 2; ++n) {
            int o = w * 32 + n * 16 + r;
            int pix0 = m * 16 + rg * 4;
            float4 v;
            v.x = acc[m][n][0]; v.y = acc[m][n][1];
            v.z = acc[m][n][2]; v.w = acc[m][n][3];
            *(float4*)(out + ((size_t)(b * 256 + o) * 64 + ho) * 64 + pix0) = v;
        }
}

// ---------------- deformable conv (fallback): inline coords -> y1p ----------------
__global__ __launch_bounds__(512, 4) void deform_inline(
    const u16* __restrict__ xh, const float* __restrict__ off,
    const u16* __restrict__ wdefh, u16* __restrict__ y1p)
{
    extern __shared__ __align__(16) char smem[];

    int blk = blockIdx.x;
    blk = (blk & 7) * 64 + (blk >> 3);
    int b = blk >> 6, ho = blk & 63;
    int t = threadIdx.x;
    int lane = t & 63, w = t >> 6;
    int r = lane & 15, kg = lane >> 4;
    int pixS = w * 8 + (lane >> 3);
    int cs   = lane & 7;

    f32x4 acc[4][2];
    f32x4 zz = {0.f, 0.f, 0.f, 0.f};
#pragma unroll
    for (int m = 0; m < 4; ++m)
#pragma unroll
        for (int n = 0; n < 2; ++n) acc[m][n] = zz;

    const u16* xB = xh + (size_t)b * (128 * 128 * 256);

    int o00, o01, o10, o11;
    float f00, f01, f10, f11;

    auto coords = [&](int k) {
        int ky = k / 3, kx = k - 3 * ky;
        float dy = off[(((size_t)b * 18 + 2 * k    ) * 64 + ho) * 64 + pixS];
        float dx = off[(((size_t)b * 18 + 2 * k + 1) * 64 + ho) * 64 + pixS];
        float py = (float)(ho * 2 - 1 + ky) + dy;
        float px = (float)(pixS * 2 - 1 + kx) + dx;
        float y0f = floorf(py), x0f = floorf(px);
        int y0 = (int)y0f, x0i = (int)x0f;
        float wy1 = py - y0f, wx1 = px - x0f;
        float wy0 = 1.f - wy1, wx0 = 1.f - wx1;
        int y1i = y0 + 1, x1i = x0i + 1;
        bool vy0 = (unsigned)y0  < 128u;
        bool vy1 = (unsigned)y1i < 128u;
        bool vx0 = (unsigned)x0i < 128u;
        bool vx1 = (unsigned)x1i < 128u;
        int yc0 = min(max(y0, 0), 127), yc1 = min(max(y1i, 0), 127);
        int xc0 = min(max(x0i, 0), 127), xc1 = min(max(x1i, 0), 127);
        o00 = yc0 * 128 + xc0;  o01 = yc0 * 128 + xc1;
        o10 = yc1 * 128 + xc0;  o11 = yc1 * 128 + xc1;
        f00 = (vy0 && vx0) ? wy0 * wx0 : 0.f;
        f01 = (vy0 && vx1) ? wy0 * wx1 : 0.f;
        f10 = (vy1 && vx0) ? wy1 * wx0 : 0.f;
        f11 = (vy1 && vx1) ? wy1 * wx1 : 0.f;
    };

    auto stage = [&](int k, int ch, int dbuf) {
        const u16* wk = wdefh + ((size_t)k << 16);
#pragma unroll
        for (int p2 = 0; p2 < 4; ++p2) {
            int i = p2 * 512 + t;
            int co = i >> 3, s = i & 7;
            gld16(wk + (size_t)co * 256 + ch * 64 + ((s ^ (co & 7)) << 3),
                  smem + dbuf * 32768 + p2 * 8192 + w * 1024);
        }
    };

    auto sample = [&](int ch, int dbuf) {
        int cw = ch * 64 + cs * 8;
        const u16* q00 = xB + (size_t)o00 * 256 + cw;
        const u16* q01 = xB + (size_t)o01 * 256 + cw;
        const u16* q10 = xB + (size_t)o10 * 256 + cw;
        const u16* q11 = xB + (size_t)o11 * 256 + cw;
        h16x8 c00 = *(const h16x8*)q00;
        h16x8 c01 = *(const h16x8*)q01;
        h16x8 c10 = *(const h16x8*)q10;
        h16x8 c11 = *(const h16x8*)q11;
        _Float16 hf00 = (_Float16)f00, hf01 = (_Float16)f01;
        _Float16 hf10 = (_Float16)f10, hf11 = (_Float16)f11;
        h16x8 v = c00 * hf00 + c01 * hf01 + c10 * hf10 + c11 * hf11;
        *(h16x8*)(smem + 65536 + dbuf * 8192 + pixS * 128 + ((cs ^ (pixS & 7)) << 4)) = v;
    };

    coords(0);
    stage(0, 0, 0);
    sample(0, 0);
    __syncthreads();

    for (int p = 0; p < 36; ++p) {
        int cur = p & 1;
        if (p < 35) {
            int pn = p + 1;
            int chn = pn / 9, kn = pn - 9 * chn;
            stage(kn, chn, cur ^ 1);
            coords(kn);
            sample(chn, cur ^ 1);
        }
        u16* wb = (u16*)(smem + cur * 32768);
        u16* sb = (u16*)(smem + 65536 + cur * 8192);
        h16x8 af[4], bfr[2];
        __builtin_amdgcn_s_setprio(1);
#pragma unroll
        for (int ksub = 0; ksub < 2; ++ksub) {
            int so = ((ksub * 4 + kg) ^ (r & 7)) << 3;
#pragma unroll
            for (int m = 0; m < 4; ++m)
                af[m] = *(h16x8*)(sb + (m * 16 + r) * 64 + so);
#pragma unroll
            for (int n = 0; n < 2; ++n)
                bfr[n] = *(h16x8*)(wb + (w * 32 + n * 16 + r) * 64 + so);
#pragma unroll
            for (int m = 0; m < 4; ++m)
#pragma unroll
                for (int n = 0; n < 2; ++n)
                    acc[m][n] = __builtin_amdgcn_mfma_f32_16x16x32_f16(af[m], bfr[n], acc[m][n], 0, 0, 0);
        }
        __builtin_amdgcn_s_setprio(0);
        __syncthreads();
    }

    u16* outT = (u16*)smem;
    int rg = lane >> 4;
#pragma unroll
    for (int m = 0; m < 4; ++m)
#pragma unroll
        for (int n = 0; n < 2; ++n) {
            int co = w * 32 + n * 16 + r;
#pragma unroll
            for (int j = 0; j < 4; ++j) {
                int prow = m * 16 + rg * 4 + j;
                outT[prow * 256 + co] = f2h(lrelu(acc[m][n][j]));
            }
        }
    __syncthreads();
    u16* dst = y1p + (size_t)(b * 64 + ho) * 16384;
#pragma unroll
    for (int p = 0; p < 4; ++p)
        *(int4*)((char*)dst + p * 8192 + t * 16) = *(int4*)(smem + p * 8192 + t * 16);
}

// ---------------- 1x1 conv: fp16 MFMA (fallback path only) ----------------
__global__ __launch_bounds__(256) void conv1x1_mfma(
    const u16* __restrict__ y1p, const u16* __restrict__ w1h,
    float* __restrict__ out)
{
    __shared__ __align__(16) char smem[20480];
    u16* btile = (u16*)smem;
    u16* atile = (u16*)(smem + 16384);

    int blk = blockIdx.x;
    blk = (blk & 7) * 64 + (blk >> 3);
    int b = blk >> 6, ho = blk & 63;
    int t = threadIdx.x, lane = t & 63, w = t >> 6;
    int r = lane & 15, kg = lane >> 4;
    int sR = (r >> 1) & 3;

    f32x4 acc[4][4];
    f32x4 zz = {0.f, 0.f, 0.f, 0.f};
#pragma unroll
    for (int m = 0; m < 4; ++m)
#pragma unroll
        for (int n = 0; n < 4; ++n) acc[m][n] = zz;

    const u16* abase = y1p + (size_t)(b * 64 + ho) * 16384;

    for (int ch = 0; ch < 8; ++ch) {
#pragma unroll
        for (int p = 0; p < 4; ++p) {
            int slot = p * 256 + t;
            int o = slot >> 2, qq = slot & 3;
            gld16(w1h + o * 256 + ch * 32 + ((qq ^ ((o >> 1) & 3)) << 3),
                  smem + p * 4096 + (t >> 6) * 1024);
        }
        {
            int pix = t >> 2, qq = t & 3;
            gld16(abase + pix * 256 + ch * 32 + ((qq ^ ((pix >> 1) & 3)) << 3),
                  smem + 16384 + (t >> 6) * 1024);
        }
        __syncthreads();
        h16x8 af[4], bfr[4];
#pragma unroll
        for (int m = 0; m < 4; ++m)
            af[m] = *(h16x8*)(atile + (m * 16 + r) * 32 + ((kg ^ sR) << 3));
#pragma unroll
        for (int n = 0; n < 4; ++n)
            bfr[n] = *(h16x8*)(btile + (w * 64 + n * 16 + r) * 32 + ((kg ^ sR) << 3));
#pragma unroll
        for (int m = 0; m < 4; ++m)
#pragma unroll
            for (int n = 0; n < 4; ++n)
                acc[m][n] = __builtin_amdgcn_mfma_f32_16x16x32_f16(af[m], bfr[n], acc[m][n], 0, 0, 0);
        __syncthreads();
    }

    int rg = lane >> 4;
#pragma unroll
    for (int m = 0; m < 4; ++m)
#pragma unroll
        for (int n = 0; n < 4; ++n) {
            int o = w * 64 + n * 16 + r;
            int pix0 = m * 16 + rg * 4;
            float4 v;
            v.x = acc[m][n][0]; v.y = acc[m][n][1];
            v.z = acc[m][n][2]; v.w = acc[m][n][3];
            *(float4*)(out + ((size_t)(b * 256 + o) * 64 + ho) * 64 + pix0) = v;
        }
}

// ---------------- instance norm + leaky, in place on d_out ----------------
__global__ __launch_bounds__(256) void instnorm(float* __restrict__ out)
{
    int bc = blockIdx.x;
    float* p = out + (size_t)bc * 4096;
    int t = threadIdx.x;

    float4 v[4];
    float s1 = 0.f, s2 = 0.f;
#pragma unroll
    for (int i = 0; i < 4; ++i) {
        v[i] = *(const float4*)&p[(t + i * 256) * 4];
        s1 += v[i].x + v[i].y + v[i].z + v[i].w;
        s2 += v[i].x * v[i].x + v[i].y * v[i].y + v[i].z * v[i].z + v[i].w * v[i].w;
    }
#pragma unroll
    for (int o = 32; o > 0; o >>= 1) {
        s1 += __shfl_down(s1, o);
        s2 += __shfl_down(s2, o);
    }
    __shared__ float rs[8];
    __shared__ float mb[2];
    int wave = t >> 6;
    if ((t & 63) == 0) { rs[wave] = s1; rs[4 + wave] = s2; }
    __syncthreads();
    if (t == 0) {
        float a = rs[0] + rs[1] + rs[2] + rs[3];
        float qq = rs[4] + rs[5] + rs[6] + rs[7];
        float mean = a * (1.f / 4096.f);
        float var  = qq * (1.f / 4096.f) - mean * mean;
        mb[0] = mean;
        mb[1] = rsqrtf(var + 1e-5f);
    }
    __syncthreads();
    float mean = mb[0], inv = mb[1];
#pragma unroll
    for (int i = 0; i < 4; ++i) {
        float4 u = v[i];
        u.x = lrelu((u.x - mean) * inv);
        u.y = lrelu((u.y - mean) * inv);
        u.z = lrelu((u.z - mean) * inv);
        u.w = lrelu((u.w - mean) * inv);
        *(float4*)&p[(t + i * 256) * 4] = u;
    }
}

extern "C" void kernel_launch(void* const* d_in, const int* in_sizes, int n_in,
                              void* d_out, int out_size, void* d_ws, size_t ws_size,
                              hipStream_t stream)
{
    const float* x     = (const float*)d_in[0];
    const float* w_off = (const float*)d_in[1];
    const float* w_def = (const float*)d_in[2];
    const float* w1    = (const float*)d_in[3];
    float* out = (float*)d_out;
    float* ws  = (float*)d_ws;

    float* off   = ws + OFF_OFS;
    u16*   wdefh = (u16*)(ws + WDEF_OFS);
    u16*   w1h   = (u16*)(ws + W1_OFS);
    u16*   wboff = (u16*)(ws + WBOFF_OFS);
    u16*   y1p   = (u16*)(ws + Y1_OFS);
    u16*   xh    = (u16*)(ws + XBF_OFS);
    int4*  tap   = (int4*)(ws + TAP_OFS);

    const bool use_tap = ws_size >= WS_NEED_TAP;   // constant per session -> deterministic

    hipFuncSetAttribute((const void*)deform_fused,
                        hipFuncAttributeMaxDynamicSharedMemorySize, 81920);
    hipFuncSetAttribute((const void*)deform_inline,
                        hipFuncAttributeMaxDynamicSharedMemorySize, 81920);

    hipLaunchKernelGGL(prep,         dim3(2304), dim3(256), 0, stream, w_def, w1, w_off, wdefh, w1h, wboff);
    hipLaunchKernelGGL(nchw2nhwc,    dim3(4096), dim3(256), 0, stream, x, xh);
    hipLaunchKernelGGL(offconv_mfma, dim3(512),  dim3(256), 0, stream, xh, wboff, off,
                       use_tap ? tap : (int4*)nullptr);
    if (use_tap) {
        hipLaunchKernelGGL(deform_fused, dim3(512), dim3(512), 81920, stream, xh, tap, wdefh, w1h, out);
    } else {
        hipLaunchKernelGGL(deform_inline, dim3(512), dim3(512), 81920, stream, xh, off, wdefh, y1p);
        hipLaunchKernelGGL(conv1x1_mfma,  dim3(512), dim3(256), 0, stream, y1p, w1h, out);
    }
    hipLaunchKernelGGL(instnorm,     dim3(2048), dim3(256), 0, stream, out);
}